// Round 14
// baseline (377.742 us; speedup 1.0000x reference)
//
#include <hip/hip_runtime.h>
#include <hip/hip_bf16.h>

// Fused additive-attention (Bahdanau-style) on MI355X.
//   att1 = enc @ W_enc + b_enc            [B,L,A]  (bf16 MFMA, fp32 accum)
//   att2 = dh @ W_dec + b_dec             [B,A]
//   s    = tanh(att1+att2) . W_full       [B,L]    (b_full dropped: softmax-invariant)
//   alpha= softmax_L(s); awe = sum_l alpha * att1  [B,A]
// Flash-style two-level softmax: att1 never hits HBM.
//
// R14: TWO CO-RESIDENT BLOCKS PER CU (never tried; every prior config was
// 1 block/CU, so barriers idled the whole CU and the 4 pipes serialized).
//   - R7 geometry: 512 thr, 8 waves, wave = 64r x 64c, acc[4][4] = 64 AGPR.
//   - SINGLE B-reg set (-32 regs vs R7) + __launch_bounds__(512,4) forcing
//     <=128 unified regs -> 4 waves/SIMD -> 2 blocks/CU co-resident.
//   - B loads just-in-time; the sibling block's waves hide L2 latency (TLP).
//   - LDS 34.5KB/block x2 = 69KB. Grid 1024 = 2 resident generations.

#define Bn 64
#define Ln 1024
#define En 2048
#define An 512
#define TM 64          // l-rows per workgroup
#define NTILES (Ln/TM) // 16
#define AWE_OFF 0
#define ALPHA_OFF (Bn*An) // 32768
#define TILEB 8192     // bytes per A k-tile LDS buffer

using short8 = __attribute__((ext_vector_type(8))) short;
using f32x4  = __attribute__((ext_vector_type(4))) float;

__device__ inline short f2bf(float x){
    unsigned u = __builtin_bit_cast(unsigned, x);
    unsigned r = (u + 0x7fffu + ((u >> 16) & 1u)) >> 16;
    return (short)r;
}
__device__ inline float tanh_fast(float x){
    return 2.0f * __frcp_rn(1.0f + __expf(-2.0f * x)) - 1.0f;
}

// ---------- kernel 0: W_enc fragment-pack  +  att2 GEMV (merged) ----------
__global__ __launch_bounds__(256) void k_prep(const float* __restrict__ W,
                                              unsigned short* __restrict__ Wp,
                                              const float* __restrict__ dh,
                                              const float* __restrict__ Wd,
                                              const float* __restrict__ bd,
                                              float* __restrict__ att2){
    __shared__ float dl[512];
    int blk = blockIdx.x, tid = threadIdx.x;
    if (blk < 512){
        int t = blk * 256 + tid;
        int f = t >> 6, lane = t & 63;
        int kb = f >> 5, nc = f & 31;
        int k0 = kb * 32 + (lane >> 4) * 8;
        int col = nc * 16 + (lane & 15);
        short8 v;
#pragma unroll
        for (int j = 0; j < 8; ++j)
            v[j] = f2bf(W[(size_t)(k0 + j) * An + col]);
        *(short8*)(Wp + (size_t)f * 512 + lane * 8) = v;
    } else {
        int b = blk - 512;
        dl[tid]       = dh[b * 512 + tid];
        dl[tid + 256] = dh[b * 512 + tid + 256];
        __syncthreads();
        for (int a = tid; a < An; a += 256){
            float s = bd[a];
            for (int k = 0; k < 512; ++k)
                s = fmaf(dl[k], Wd[(size_t)k * An + a], s);
            att2[b * An + a] = s;
        }
    }
}

// ---------- kernel 1: fused GEMM + score + tile-softmax + partial awe ----------
// 512 threads = 8 waves, wave w owns rows 0..63 x cols [w*64, w*64+64).

#define MFMA(a, b, c) __builtin_amdgcn_mfma_f32_16x16x32_bf16((a), (b), (c), 0, 0, 0)

// Just-in-time B loads for phase P (8 frags, 64 cols) into the single set.
#define BLOADF(P)                                                             \
    { int pc = (P) > 31 ? 31 : (P);                                           \
      const unsigned short* bp = Bbase + (size_t)pc * 32768;                  \
      f00 = *(const short8*)(bp);                                             \
      f01 = *(const short8*)(bp + 512);                                       \
      f02 = *(const short8*)(bp + 1024);                                      \
      f03 = *(const short8*)(bp + 1536);                                      \
      f10 = *(const short8*)(bp + 16384);                                     \
      f11 = *(const short8*)(bp + 16384 + 512);                               \
      f12 = *(const short8*)(bp + 16384 + 1024);                              \
      f13 = *(const short8*)(bp + 16384 + 1536); }

#define STAGE(Q, R0, R1)                                                      \
    { short8 sv;                                                              \
      sv[0] = f2bf(R0.x); sv[1] = f2bf(R0.y);                                 \
      sv[2] = f2bf(R0.z); sv[3] = f2bf(R0.w);                                 \
      sv[4] = f2bf(R1.x); sv[5] = f2bf(R1.y);                                 \
      sv[6] = f2bf(R1.z); sv[7] = f2bf(R1.w);                                 \
      *(short8*)(swp + (Q) * TILEB) = sv; }

// 32 MFMAs for buffer Q using the single (just-loaded) B set.
#define MFMAS(Q)                                                              \
    __builtin_amdgcn_s_setprio(1);                                            \
    _Pragma("unroll")                                                         \
    for (int mi = 0; mi < 4; ++mi){                                           \
        short8 af0 = *(const short8*)(as0 + (Q) * TILEB + mi * 2048);         \
        short8 af1 = *(const short8*)(as1 + (Q) * TILEB + mi * 2048);         \
        acc[mi][0] = MFMA(af0, f00, acc[mi][0]);                              \
        acc[mi][1] = MFMA(af0, f01, acc[mi][1]);                              \
        acc[mi][2] = MFMA(af0, f02, acc[mi][2]);                              \
        acc[mi][3] = MFMA(af0, f03, acc[mi][3]);                              \
        acc[mi][0] = MFMA(af1, f10, acc[mi][0]);                              \
        acc[mi][1] = MFMA(af1, f11, acc[mi][1]);                              \
        acc[mi][2] = MFMA(af1, f12, acc[mi][2]);                              \
        acc[mi][3] = MFMA(af1, f13, acc[mi][3]);                              \
    }                                                                         \
    __builtin_amdgcn_s_setprio(0);

// Raw barrier: drain LDS ops only; global loads stay in flight.
#define PBAR                                                                  \
    __builtin_amdgcn_sched_barrier(0);                                        \
    asm volatile("s_waitcnt lgkmcnt(0)");                                     \
    __builtin_amdgcn_s_barrier();                                             \
    __builtin_amdgcn_sched_barrier(0)

__global__ __launch_bounds__(512, 4)
void k_main(const float* __restrict__ enc, const unsigned short* __restrict__ Wp,
            const float* __restrict__ benc, const float* __restrict__ att2,
            const float* __restrict__ wfull, float* __restrict__ out,
            float* __restrict__ pawe_ws, float* __restrict__ ms_ws){
    const int wg   = blockIdx.x;            // 0..1023
    const int b    = wg >> 4;
    const int tile = wg & 15;
    const int l0   = tile * TM;
    const int tid  = threadIdx.x;
    const int lane = tid & 63, w = tid >> 6;   // w = 0..7 (col-group)

    __shared__ alignas(16) unsigned short Alds[4][TM * 64];  // 4 x 8 KB, XOR-swizzled
    __shared__ float red[8][TM];               // per-wave row score partials
    __shared__ float plds[TM];                 // tile-local exp(s - m)
    char* const alds = (char*)Alds;

    f32x4 acc[4][4];
#pragma unroll
    for (int mi = 0; mi < 4; ++mi)
#pragma unroll
        for (int ni = 0; ni < 4; ++ni)
            acc[mi][ni] = (f32x4){0.f, 0.f, 0.f, 0.f};

    // staging: thread loads 8 fp32 (2x16B) of row (tid>>3), k-chunk (tid&7)*8
    const int srow  = tid >> 3;
    const int sbyte = srow * 128 + (((tid & 7) * 16) ^ ((srow & 7) << 4));
    char* const swp = alds + sbyte;
    const float* apt = enc + ((size_t)(b * Ln + l0 + srow)) * En + (tid & 7) * 8;

    // B fragments: f = (p*2+s)*32 + w*4 + ni ; addr = Wp + f*512 + lane*8
    const unsigned short* Bbase = Wp + (size_t)(w * 4) * 512 + lane * 8;

    // A fragments: row = mi*16 + (lane&15); k-byte = (s*64 + akb) ^ sw (full XOR)
    const int arow = lane & 15;
    const int akb  = (lane >> 4) * 16;
    const int sw   = (arow & 7) << 4;
    const char* const as0 = alds + arow * 128 + (akb ^ sw);
    const char* const as1 = alds + arow * 128 + ((64 + akb) ^ sw);

    // single B register set (just-in-time loads; TLP hides L2 latency)
    short8 f00, f01, f02, f03, f10, f11, f12, f13;

    // prologue: tiles 0,1 staged; ring (ra*,rb*) holds tiles 2,3
    float4 ra0 = *(const float4*)(apt);
    float4 ra1 = *(const float4*)(apt + 4);
    float4 rb0 = *(const float4*)(apt + 64);
    float4 rb1 = *(const float4*)(apt + 68);
    STAGE(0, ra0, ra1)
    STAGE(1, rb0, rb1)
    ra0 = *(const float4*)(apt + 2 * 64);
    ra1 = *(const float4*)(apt + 2 * 64 + 4);
    rb0 = *(const float4*)(apt + 3 * 64);
    rb1 = *(const float4*)(apt + 3 * 64 + 4);

    for (int p = 0; p < 32; p += 4){
        PBAR;
        {   // phase p: stage p+2,p+3 -> Q2,Q3; reload ring; MFMA Q0
            BLOADF(p)
            STAGE(2, ra0, ra1)
            STAGE(3, rb0, rb1)
            int t0 = p + 4 > 31 ? 31 : p + 4;
            int t1 = p + 5 > 31 ? 31 : p + 5;
            ra0 = *(const float4*)(apt + t0 * 64);
            ra1 = *(const float4*)(apt + t0 * 64 + 4);
            rb0 = *(const float4*)(apt + t1 * 64);
            rb1 = *(const float4*)(apt + t1 * 64 + 4);
            MFMAS(0)
        }
        {   // phase p+1: MFMA Q1
            BLOADF(p + 1)
            MFMAS(1)
        }
        PBAR;
        {   // phase p+2: stage p+4,p+5 -> Q0,Q1; reload ring; MFMA Q2
            BLOADF(p + 2)
            STAGE(0, ra0, ra1)
            STAGE(1, rb0, rb1)
            int t0 = p + 6 > 31 ? 31 : p + 6;
            int t1 = p + 7 > 31 ? 31 : p + 7;
            ra0 = *(const float4*)(apt + t0 * 64);
            ra1 = *(const float4*)(apt + t0 * 64 + 4);
            rb0 = *(const float4*)(apt + t1 * 64);
            rb1 = *(const float4*)(apt + t1 * 64 + 4);
            MFMAS(2)
        }
        {   // phase p+3: MFMA Q3
            BLOADF(p + 3)
            MFMAS(3)
        }
    }

    // ---- epilogue ----
    float be[4], a2[4], wfv[4];
    const int cbase = w * 64 + (lane & 15);
#pragma unroll
    for (int ni = 0; ni < 4; ++ni){
        int c = cbase + ni * 16;
        be[ni]  = benc[c];
        a2[ni]  = att2[b * An + c];
        wfv[ni] = wfull[c];
    }

    float tsum[4][4];
#pragma unroll
    for (int mi = 0; mi < 4; ++mi)
#pragma unroll
        for (int j = 0; j < 4; ++j)
            tsum[mi][j] = 0.f;
#pragma unroll
    for (int mi = 0; mi < 4; ++mi)
#pragma unroll
        for (int ni = 0; ni < 4; ++ni)
#pragma unroll
            for (int j = 0; j < 4; ++j){
                float vv = acc[mi][ni][j] + be[ni];
                acc[mi][ni][j] = vv;
                tsum[mi][j] += tanh_fast(vv + a2[ni]) * wfv[ni];
            }

#pragma unroll
    for (int mi = 0; mi < 4; ++mi)
#pragma unroll
        for (int j = 0; j < 4; ++j){
            float t = tsum[mi][j];
            t += __shfl_xor(t, 1); t += __shfl_xor(t, 2);
            t += __shfl_xor(t, 4); t += __shfl_xor(t, 8);
            if ((lane & 15) == 0)
                red[w][mi * 16 + (lane >> 4) * 4 + j] = t;
        }
    __syncthreads();

    if (tid < 64){   // wave 0: combine 8 wave-partials, tile softmax stats
        float s = 0.f;
#pragma unroll
        for (int k = 0; k < 8; ++k)
            s += red[k][tid];
        out[ALPHA_OFF + b * Ln + l0 + tid] = s;   // raw score; finalized in k_final
        float m = s;
        m = fmaxf(m, __shfl_xor(m, 1));  m = fmaxf(m, __shfl_xor(m, 2));
        m = fmaxf(m, __shfl_xor(m, 4));  m = fmaxf(m, __shfl_xor(m, 8));
        m = fmaxf(m, __shfl_xor(m, 16)); m = fmaxf(m, __shfl_xor(m, 32));
        float pv = __expf(s - m);
        float sm = pv;
        sm += __shfl_xor(sm, 1);  sm += __shfl_xor(sm, 2);
        sm += __shfl_xor(sm, 4);  sm += __shfl_xor(sm, 8);
        sm += __shfl_xor(sm, 16); sm += __shfl_xor(sm, 32);
        plds[tid] = pv;
        if (tid == 0){ ms_ws[wg * 2] = m; ms_ws[wg * 2 + 1] = sm; }
    }
    __syncthreads();

    // partial awe for this wave's 64 cols (rows complete within the wave)
    float pp[4];
#pragma unroll
    for (int ni = 0; ni < 4; ++ni) pp[ni] = 0.f;
#pragma unroll
    for (int mi = 0; mi < 4; ++mi)
#pragma unroll
        for (int j = 0; j < 4; ++j){
            float pr = plds[mi * 16 + (lane >> 4) * 4 + j];
#pragma unroll
            for (int ni = 0; ni < 4; ++ni)
                pp[ni] += pr * acc[mi][ni][j];
        }
#pragma unroll
    for (int ni = 0; ni < 4; ++ni){
        pp[ni] += __shfl_xor(pp[ni], 16);
        pp[ni] += __shfl_xor(pp[ni], 32);
    }
    if (lane < 16){
#pragma unroll
        for (int ni = 0; ni < 4; ++ni)
            pawe_ws[(size_t)wg * An + w * 64 + ni * 16 + lane] = pp[ni];
    }
}

// ---------- kernel 2: combine tiles, finalize awe + alpha ----------
__global__ __launch_bounds__(256) void k_final(const float* __restrict__ pawe,
                                               const float* __restrict__ ms,
                                               float* __restrict__ out){
    int b = blockIdx.x, tid = threadIdx.x;
    __shared__ float scale[NTILES];
    __shared__ float sh[2];   // inv_total, global max
    if (tid < 64){
        int lane = tid;
        float m = -1e30f, su = 0.f;
        if (lane < NTILES){ m = ms[(b * NTILES + lane) * 2]; su = ms[(b * NTILES + lane) * 2 + 1]; }
        float mm = m;
        mm = fmaxf(mm, __shfl_xor(mm, 1)); mm = fmaxf(mm, __shfl_xor(mm, 2));
        mm = fmaxf(mm, __shfl_xor(mm, 4)); mm = fmaxf(mm, __shfl_xor(mm, 8));
        float sc = (lane < NTILES) ? su * __expf(m - mm) : 0.f;
        float tot = sc;
        tot += __shfl_xor(tot, 1); tot += __shfl_xor(tot, 2);
        tot += __shfl_xor(tot, 4); tot += __shfl_xor(tot, 8);
        if (lane < NTILES) scale[lane] = __expf(m - mm);
        if (lane == 0){ sh[0] = 1.0f / tot; sh[1] = mm; }
    }
    __syncthreads();
    float inv = sh[0], mm = sh[1];
    for (int a = tid; a < An; a += 256){
        float s = 0.f;
#pragma unroll
        for (int t = 0; t < NTILES; ++t)
            s += pawe[((size_t)(b * NTILES + t)) * An + a] * scale[t];
        out[AWE_OFF + b * An + a] = s * inv;
    }
    for (int l = tid; l < Ln; l += 256){
        float s = out[ALPHA_OFF + b * Ln + l];
        out[ALPHA_OFF + b * Ln + l] = __expf(s - mm) * inv;
    }
}

extern "C" void kernel_launch(void* const* d_in, const int* in_sizes, int n_in,
                              void* d_out, int out_size, void* d_ws, size_t ws_size,
                              hipStream_t stream){
    const float* enc   = (const float*)d_in[0];
    const float* dh    = (const float*)d_in[1];
    const float* Wenc  = (const float*)d_in[2];
    const float* benc  = (const float*)d_in[3];
    const float* Wdec  = (const float*)d_in[4];
    const float* bdec  = (const float*)d_in[5];
    const float* wfull = (const float*)d_in[6];
    // d_in[7] = b_full: softmax-invariant, unused.
    float* out = (float*)d_out;

    char* ws = (char*)d_ws;
    unsigned short* Wp = (unsigned short*)ws;                       // 2 MB packed W
    float* att2 = (float*)(ws + (2u << 20));                        // 128 KB
    float* pawe = (float*)(ws + (2u << 20) + (128u << 10));         // 2 MB
    float* msb  = (float*)(ws + (4u << 20) + (128u << 10));         // 8 KB

    k_prep<<<576, 256, 0, stream>>>(Wenc, Wp, dh, Wdec, bdec, att2);
    k_main<<<Bn * NTILES, 512, 0, stream>>>(enc, Wp, benc, att2, wfull, out, pawe, msb);
    k_final<<<Bn, 256, 0, stream>>>(pawe, msb, out);
}

// Round 15
// 288.937 us; speedup vs baseline: 1.3073x; 1.3073x over previous
//
#include <hip/hip_runtime.h>
#include <hip/hip_bf16.h>

// Fused additive-attention (Bahdanau-style) on MI355X.
//   att1 = enc @ W_enc + b_enc            [B,L,A]  (bf16 MFMA, fp32 accum)
//   att2 = dh @ W_dec + b_dec             [B,A]
//   s    = tanh(att1+att2) . W_full       [B,L]    (b_full dropped: softmax-invariant)
//   alpha= softmax_L(s); awe = sum_l alpha * att1  [B,A]
// Flash-style two-level softmax: att1 never hits HBM.
//
// R15 = R8 geometry (TM=128: halves per-CU L2-B traffic, the #2 floor) with
// R8's spill fixed + R11's counted-vmcnt barrier:
//   - EPILOGUE SPILL FIX: tsum reduced per-mi immediately (4 regs reused,
//     was [8][4]=32 live) -> epilogue peak ~= acc64 + 14 VGPR, no scratch.
//   - main loop: acc[8][2]=64 AGPR + B dbl-set 32 + ring 16 + addr ~12 ~= 124.
//   - PBAR (lgkmcnt-only barrier, m201 pattern): global loads stay in flight.
// Pre-commit: WRITE_SIZE > 10MB => spill again, revert; >=240us clean =>
// L2-B not the serializer, declare plateau at R11.

#define Bn 64
#define Ln 1024
#define En 2048
#define An 512
#define TM 128         // l-rows per workgroup
#define NTILES (Ln/TM) // 8
#define AWE_OFF 0
#define ALPHA_OFF (Bn*An) // 32768
#define TILEB 16384    // bytes per A k-tile LDS buffer (128 rows x 128B)

using short8 = __attribute__((ext_vector_type(8))) short;
using f32x4  = __attribute__((ext_vector_type(4))) float;

__device__ inline short f2bf(float x){
    unsigned u = __builtin_bit_cast(unsigned, x);
    unsigned r = (u + 0x7fffu + ((u >> 16) & 1u)) >> 16;
    return (short)r;
}
__device__ inline float tanh_fast(float x){
    return 2.0f * __frcp_rn(1.0f + __expf(-2.0f * x)) - 1.0f;
}

// ---------- kernel 0: W_enc fragment-pack  +  att2 GEMV (merged) ----------
__global__ __launch_bounds__(256) void k_prep(const float* __restrict__ W,
                                              unsigned short* __restrict__ Wp,
                                              const float* __restrict__ dh,
                                              const float* __restrict__ Wd,
                                              const float* __restrict__ bd,
                                              float* __restrict__ att2){
    __shared__ float dl[512];
    int blk = blockIdx.x, tid = threadIdx.x;
    if (blk < 512){
        int t = blk * 256 + tid;
        int f = t >> 6, lane = t & 63;
        int kb = f >> 5, nc = f & 31;
        int k0 = kb * 32 + (lane >> 4) * 8;
        int col = nc * 16 + (lane & 15);
        short8 v;
#pragma unroll
        for (int j = 0; j < 8; ++j)
            v[j] = f2bf(W[(size_t)(k0 + j) * An + col]);
        *(short8*)(Wp + (size_t)f * 512 + lane * 8) = v;
    } else {
        int b = blk - 512;
        dl[tid]       = dh[b * 512 + tid];
        dl[tid + 256] = dh[b * 512 + tid + 256];
        __syncthreads();
        for (int a = tid; a < An; a += 256){
            float s = bd[a];
            for (int k = 0; k < 512; ++k)
                s = fmaf(dl[k], Wd[(size_t)k * An + a], s);
            att2[b * An + a] = s;
        }
    }
}

// ---------- kernel 1: fused GEMM + score + tile-softmax + partial awe ----------
// 1024 threads = 16 waves, wave w owns ALL 128 rows x cols [w*32, w*32+32).
// acc[mi][ni]: mi = row block (mi*16, 0..7), ni = col block (w*32 + ni*16).

#define MFMA(a, b, c) __builtin_amdgcn_mfma_f32_16x16x32_bf16((a), (b), (c), 0, 0, 0)

// Issue phase-P B loads (4 frags: s in {0,1} x ni in {0,1}) into set S.
#define BLOAD(S, P)                                                           \
    { int pc = (P) > 31 ? 31 : (P);                                           \
      const unsigned short* bp = Bbase + (size_t)pc * 32768;                  \
      S##00 = *(const short8*)(bp);                                           \
      S##01 = *(const short8*)(bp + 512);                                     \
      S##10 = *(const short8*)(bp + 16384);                                   \
      S##11 = *(const short8*)(bp + 16384 + 512); }

#define STAGE(Q, R0, R1)                                                      \
    { short8 sv;                                                              \
      sv[0] = f2bf(R0.x); sv[1] = f2bf(R0.y);                                 \
      sv[2] = f2bf(R0.z); sv[3] = f2bf(R0.w);                                 \
      sv[4] = f2bf(R1.x); sv[5] = f2bf(R1.y);                                 \
      sv[6] = f2bf(R1.z); sv[7] = f2bf(R1.w);                                 \
      *(short8*)(swp + (Q) * TILEB) = sv; }

// 16 MFMAs for buffer Q using landed register set S.
#define MFMAS(Q, S)                                                           \
    __builtin_amdgcn_s_setprio(1);                                            \
    _Pragma("unroll")                                                         \
    for (int mi = 0; mi < 8; ++mi){                                           \
        short8 af0 = *(const short8*)(as0 + (Q) * TILEB + mi * 2048);         \
        short8 af1 = *(const short8*)(as1 + (Q) * TILEB + mi * 2048);         \
        acc[mi][0] = MFMA(af0, S##00, acc[mi][0]);                            \
        acc[mi][1] = MFMA(af0, S##01, acc[mi][1]);                            \
        acc[mi][0] = MFMA(af1, S##10, acc[mi][0]);                            \
        acc[mi][1] = MFMA(af1, S##11, acc[mi][1]);                            \
    }                                                                         \
    __builtin_amdgcn_s_setprio(0);

// Raw barrier (m201 pattern): drain LDS ops only; no memory clobber ->
// global loads stay in flight; sched_barrier(0) = compiler fence.
#define PBAR                                                                  \
    __builtin_amdgcn_sched_barrier(0);                                        \
    asm volatile("s_waitcnt lgkmcnt(0)");                                     \
    __builtin_amdgcn_s_barrier();                                             \
    __builtin_amdgcn_sched_barrier(0)

__global__ __launch_bounds__(1024)
void k_main(const float* __restrict__ enc, const unsigned short* __restrict__ Wp,
            const float* __restrict__ benc, const float* __restrict__ att2,
            const float* __restrict__ wfull, float* __restrict__ out,
            float* __restrict__ pawe_ws, float* __restrict__ ms_ws){
    const int wg   = blockIdx.x;            // 0..511
    const int b    = wg >> 3;
    const int tile = wg & 7;
    const int l0   = tile * TM;
    const int tid  = threadIdx.x;
    const int lane = tid & 63, w = tid >> 6;   // w = 0..15 (col-group)

    __shared__ alignas(16) unsigned short Alds[4][TM * 64];  // 4 x 16 KB, XOR-swizzled
    __shared__ float red[16][TM];              // per-wave row score partials (8 KB)
    __shared__ float pl[TM];                   // tile-local exp(s - m)
    __shared__ float mred[2], sred[2];
    char* const alds = (char*)Alds;

    f32x4 acc[8][2];
#pragma unroll
    for (int mi = 0; mi < 8; ++mi)
#pragma unroll
        for (int ni = 0; ni < 2; ++ni)
            acc[mi][ni] = (f32x4){0.f, 0.f, 0.f, 0.f};

    // staging: thread loads 8 fp32 (2x16B) of row (tid>>3), k-chunk (tid&7)*8
    const int srow  = tid >> 3;
    const int sbyte = srow * 128 + (((tid & 7) * 16) ^ ((srow & 7) << 4));
    char* const swp = alds + sbyte;
    const float* apt = enc + ((size_t)(b * Ln + l0 + srow)) * En + (tid & 7) * 8;

    // B fragments: f = (p*2+s)*32 + w*2 + ni ; addr = Wp + f*512 + lane*8
    const unsigned short* Bbase = Wp + (size_t)(w * 2) * 512 + lane * 8;

    // A fragments: row = mi*16 + (lane&15); k-byte = (s*64 + akb) ^ sw (full XOR)
    const int arow = lane & 15;
    const int akb  = (lane >> 4) * 16;
    const int sw   = (arow & 7) << 4;
    const char* const as0 = alds + arow * 128 + (akb ^ sw);
    const char* const as1 = alds + arow * 128 + ((64 + akb) ^ sw);

    // B register sets (double-buffered across phases)
    short8 fa00, fa01, fa10, fa11;   // even phases
    short8 fb00, fb01, fb10, fb11;   // odd phases

    // prologue: tiles 0,1 staged; ring (ra*,rb*) holds tiles 2,3; B(0) in fa
    float4 ra0 = *(const float4*)(apt);
    float4 ra1 = *(const float4*)(apt + 4);
    float4 rb0 = *(const float4*)(apt + 64);
    float4 rb1 = *(const float4*)(apt + 68);
    STAGE(0, ra0, ra1)
    STAGE(1, rb0, rb1)
    ra0 = *(const float4*)(apt + 2 * 64);
    ra1 = *(const float4*)(apt + 2 * 64 + 4);
    rb0 = *(const float4*)(apt + 3 * 64);
    rb1 = *(const float4*)(apt + 3 * 64 + 4);
    BLOAD(fa, 0)

    for (int p = 0; p < 32; p += 4){
        PBAR;
        {   // phase p: issue B(p+1); stage p+2,p+3 -> Q2,Q3; reload ring; MFMA Q0 (fa)
            BLOAD(fb, p + 1)
            STAGE(2, ra0, ra1)
            STAGE(3, rb0, rb1)
            int t0 = p + 4 > 31 ? 31 : p + 4;   // clamped tail loads (unread)
            int t1 = p + 5 > 31 ? 31 : p + 5;
            ra0 = *(const float4*)(apt + t0 * 64);
            ra1 = *(const float4*)(apt + t0 * 64 + 4);
            rb0 = *(const float4*)(apt + t1 * 64);
            rb1 = *(const float4*)(apt + t1 * 64 + 4);
            MFMAS(0, fa)
        }
        {   // phase p+1: issue B(p+2); MFMA Q1 (fb)
            BLOAD(fa, p + 2)
            MFMAS(1, fb)
        }
        PBAR;
        {   // phase p+2: issue B(p+3); stage p+4,p+5 -> Q0,Q1; reload ring; MFMA Q2 (fa)
            BLOAD(fb, p + 3)
            STAGE(0, ra0, ra1)
            STAGE(1, rb0, rb1)
            int t0 = p + 6 > 31 ? 31 : p + 6;
            int t1 = p + 7 > 31 ? 31 : p + 7;
            ra0 = *(const float4*)(apt + t0 * 64);
            ra1 = *(const float4*)(apt + t0 * 64 + 4);
            rb0 = *(const float4*)(apt + t1 * 64);
            rb1 = *(const float4*)(apt + t1 * 64 + 4);
            MFMAS(2, fa)
        }
        {   // phase p+3: issue B(p+4); MFMA Q3 (fb)
            BLOAD(fa, p + 4)
            MFMAS(3, fb)
        }
    }

    // ---- epilogue ----
    float be[2], a2[2], wfv[2];
    const int cbase = w * 32 + (lane & 15);
#pragma unroll
    for (int ni = 0; ni < 2; ++ni){
        int c = cbase + ni * 16;
        be[ni]  = benc[c];
        a2[ni]  = att2[b * An + c];
        wfv[ni] = wfull[c];
    }

    // SPILL FIX: per-mi immediate score reduction — only 4 tsum regs live.
#pragma unroll
    for (int mi = 0; mi < 8; ++mi){
        float ts0 = 0.f, ts1 = 0.f, ts2 = 0.f, ts3 = 0.f;
#pragma unroll
        for (int ni = 0; ni < 2; ++ni){
            float v0 = acc[mi][ni][0] + be[ni]; acc[mi][ni][0] = v0;
            float v1 = acc[mi][ni][1] + be[ni]; acc[mi][ni][1] = v1;
            float v2 = acc[mi][ni][2] + be[ni]; acc[mi][ni][2] = v2;
            float v3 = acc[mi][ni][3] + be[ni]; acc[mi][ni][3] = v3;
            ts0 += tanh_fast(v0 + a2[ni]) * wfv[ni];
            ts1 += tanh_fast(v1 + a2[ni]) * wfv[ni];
            ts2 += tanh_fast(v2 + a2[ni]) * wfv[ni];
            ts3 += tanh_fast(v3 + a2[ni]) * wfv[ni];
        }
        float t4[4] = {ts0, ts1, ts2, ts3};
#pragma unroll
        for (int j = 0; j < 4; ++j){
            float t = t4[j];
            t += __shfl_xor(t, 1); t += __shfl_xor(t, 2);
            t += __shfl_xor(t, 4); t += __shfl_xor(t, 8);
            if ((lane & 15) == 0)
                red[w][mi * 16 + (lane >> 4) * 4 + j] = t;
        }
    }
    __syncthreads();

    // tile softmax over TM=128 rows, handled by waves 0 and 1
    float sc_s = 0.f;
    if (tid < TM){
        const int w2 = tid >> 6;
#pragma unroll
        for (int k = 0; k < 16; ++k)
            sc_s += red[k][tid];
        out[ALPHA_OFF + b * Ln + l0 + tid] = sc_s;   // raw score; finalized in k_final
        float m = sc_s;
        m = fmaxf(m, __shfl_xor(m, 1));  m = fmaxf(m, __shfl_xor(m, 2));
        m = fmaxf(m, __shfl_xor(m, 4));  m = fmaxf(m, __shfl_xor(m, 8));
        m = fmaxf(m, __shfl_xor(m, 16)); m = fmaxf(m, __shfl_xor(m, 32));
        if ((tid & 63) == 0) mred[w2] = m;
    }
    __syncthreads();
    if (tid < TM){
        const int w2 = tid >> 6;
        float mm = fmaxf(mred[0], mred[1]);
        float pv = __expf(sc_s - mm);
        pl[tid] = pv;
        float sm = pv;
        sm += __shfl_xor(sm, 1);  sm += __shfl_xor(sm, 2);
        sm += __shfl_xor(sm, 4);  sm += __shfl_xor(sm, 8);
        sm += __shfl_xor(sm, 16); sm += __shfl_xor(sm, 32);
        if ((tid & 63) == 0) sred[w2] = sm;
    }
    __syncthreads();
    if (tid == 0){
        ms_ws[wg * 2]     = fmaxf(mred[0], mred[1]);
        ms_ws[wg * 2 + 1] = sred[0] + sred[1];
    }

    // partial awe for this wave's 32 cols (ALL 128 rows live in this wave)
    float pp0 = 0.f, pp1 = 0.f;
#pragma unroll
    for (int mi = 0; mi < 8; ++mi)
#pragma unroll
        for (int j = 0; j < 4; ++j){
            float pr = pl[mi * 16 + (lane >> 4) * 4 + j];
            pp0 += pr * acc[mi][0][j];
            pp1 += pr * acc[mi][1][j];
        }
    pp0 += __shfl_xor(pp0, 16); pp0 += __shfl_xor(pp0, 32);
    pp1 += __shfl_xor(pp1, 16); pp1 += __shfl_xor(pp1, 32);
    if (lane < 16){
        pawe_ws[(size_t)wg * An + w * 32 + lane]      = pp0;
        pawe_ws[(size_t)wg * An + w * 32 + 16 + lane] = pp1;
    }
}

// ---------- kernel 2: combine tiles, finalize awe + alpha ----------
__global__ __launch_bounds__(256) void k_final(const float* __restrict__ pawe,
                                               const float* __restrict__ ms,
                                               float* __restrict__ out){
    int b = blockIdx.x, tid = threadIdx.x;
    __shared__ float scale[NTILES];
    __shared__ float sh[2];   // inv_total, global max
    if (tid < 64){
        int lane = tid;
        float m = -1e30f, su = 0.f;
        if (lane < NTILES){ m = ms[(b * NTILES + lane) * 2]; su = ms[(b * NTILES + lane) * 2 + 1]; }
        float mm = m;
        mm = fmaxf(mm, __shfl_xor(mm, 1)); mm = fmaxf(mm, __shfl_xor(mm, 2));
        mm = fmaxf(mm, __shfl_xor(mm, 4));
        float sc = (lane < NTILES) ? su * __expf(m - mm) : 0.f;
        float tot = sc;
        tot += __shfl_xor(tot, 1); tot += __shfl_xor(tot, 2);
        tot += __shfl_xor(tot, 4);
        if (lane < NTILES) scale[lane] = __expf(m - mm);
        if (lane == 0){ sh[0] = 1.0f / tot; sh[1] = mm; }
    }
    __syncthreads();
    float inv = sh[0], mm = sh[1];
    for (int a = tid; a < An; a += 256){
        float s = 0.f;
#pragma unroll
        for (int t = 0; t < NTILES; ++t)
            s += pawe[((size_t)(b * NTILES + t)) * An + a] * scale[t];
        out[AWE_OFF + b * An + a] = s * inv;
    }
    for (int l = tid; l < Ln; l += 256){
        float s = out[ALPHA_OFF + b * Ln + l];
        out[ALPHA_OFF + b * Ln + l] = __expf(s - mm) * inv;
    }
}

extern "C" void kernel_launch(void* const* d_in, const int* in_sizes, int n_in,
                              void* d_out, int out_size, void* d_ws, size_t ws_size,
                              hipStream_t stream){
    const float* enc   = (const float*)d_in[0];
    const float* dh    = (const float*)d_in[1];
    const float* Wenc  = (const float*)d_in[2];
    const float* benc  = (const float*)d_in[3];
    const float* Wdec  = (const float*)d_in[4];
    const float* bdec  = (const float*)d_in[5];
    const float* wfull = (const float*)d_in[6];
    // d_in[7] = b_full: softmax-invariant, unused.
    float* out = (float*)d_out;

    char* ws = (char*)d_ws;
    unsigned short* Wp = (unsigned short*)ws;                       // 2 MB packed W
    float* att2 = (float*)(ws + (2u << 20));                        // 128 KB
    float* pawe = (float*)(ws + (2u << 20) + (128u << 10));         // 1 MB (512 wg x 512)
    float* msb  = (float*)(ws + (4u << 20) + (128u << 10));         // 4 KB

    k_prep<<<576, 256, 0, stream>>>(Wenc, Wp, dh, Wdec, bdec, att2);
    k_main<<<Bn * NTILES, 1024, 0, stream>>>(enc, Wp, benc, att2, wfull, out, pawe, msb);
    k_final<<<Bn, 256, 0, stream>>>(pawe, msb, out);
}

// Round 16
// 287.509 us; speedup vs baseline: 1.3138x; 1.0050x over previous
//
#include <hip/hip_runtime.h>
#include <hip/hip_bf16.h>

// Fused additive-attention (Bahdanau-style) on MI355X.
//   att1 = enc @ W_enc + b_enc            [B,L,A]  (bf16 MFMA, fp32 accum)
//   att2 = dh @ W_dec + b_dec             [B,A]
//   s    = tanh(att1+att2) . W_full       [B,L]    (b_full dropped: softmax-invariant)
//   alpha= softmax_L(s); awe = sum_l alpha * att1  [B,A]
// Flash-style two-level softmax: att1 never hits HBM.
//
// R15 = R8 geometry (TM=128: halves per-CU L2-B traffic, the #2 floor) with
// R8's spill fixed + R11's counted-vmcnt barrier:
//   - EPILOGUE SPILL FIX: tsum reduced per-mi immediately (4 regs reused,
//     was [8][4]=32 live) -> epilogue peak ~= acc64 + 14 VGPR, no scratch.
//   - main loop: acc[8][2]=64 AGPR + B dbl-set 32 + ring 16 + addr ~12 ~= 124.
//   - PBAR (lgkmcnt-only barrier, m201 pattern): global loads stay in flight.
// Pre-commit: WRITE_SIZE > 10MB => spill again, revert; >=240us clean =>
// L2-B not the serializer, declare plateau at R11.

#define Bn 64
#define Ln 1024
#define En 2048
#define An 512
#define TM 128         // l-rows per workgroup
#define NTILES (Ln/TM) // 8
#define AWE_OFF 0
#define ALPHA_OFF (Bn*An) // 32768
#define TILEB 16384    // bytes per A k-tile LDS buffer (128 rows x 128B)

using short8 = __attribute__((ext_vector_type(8))) short;
using f32x4  = __attribute__((ext_vector_type(4))) float;

__device__ inline short f2bf(float x){
    unsigned u = __builtin_bit_cast(unsigned, x);
    unsigned r = (u + 0x7fffu + ((u >> 16) & 1u)) >> 16;
    return (short)r;
}
__device__ inline float tanh_fast(float x){
    return 2.0f * __frcp_rn(1.0f + __expf(-2.0f * x)) - 1.0f;
}

// ---------- kernel 0: W_enc fragment-pack  +  att2 GEMV (merged) ----------
__global__ __launch_bounds__(256) void k_prep(const float* __restrict__ W,
                                              unsigned short* __restrict__ Wp,
                                              const float* __restrict__ dh,
                                              const float* __restrict__ Wd,
                                              const float* __restrict__ bd,
                                              float* __restrict__ att2){
    __shared__ float dl[512];
    int blk = blockIdx.x, tid = threadIdx.x;
    if (blk < 512){
        int t = blk * 256 + tid;
        int f = t >> 6, lane = t & 63;
        int kb = f >> 5, nc = f & 31;
        int k0 = kb * 32 + (lane >> 4) * 8;
        int col = nc * 16 + (lane & 15);
        short8 v;
#pragma unroll
        for (int j = 0; j < 8; ++j)
            v[j] = f2bf(W[(size_t)(k0 + j) * An + col]);
        *(short8*)(Wp + (size_t)f * 512 + lane * 8) = v;
    } else {
        int b = blk - 512;
        dl[tid]       = dh[b * 512 + tid];
        dl[tid + 256] = dh[b * 512 + tid + 256];
        __syncthreads();
        for (int a = tid; a < An; a += 256){
            float s = bd[a];
            for (int k = 0; k < 512; ++k)
                s = fmaf(dl[k], Wd[(size_t)k * An + a], s);
            att2[b * An + a] = s;
        }
    }
}

// ---------- kernel 1: fused GEMM + score + tile-softmax + partial awe ----------
// 1024 threads = 16 waves, wave w owns ALL 128 rows x cols [w*32, w*32+32).
// acc[mi][ni]: mi = row block (mi*16, 0..7), ni = col block (w*32 + ni*16).

#define MFMA(a, b, c) __builtin_amdgcn_mfma_f32_16x16x32_bf16((a), (b), (c), 0, 0, 0)

// Issue phase-P B loads (4 frags: s in {0,1} x ni in {0,1}) into set S.
#define BLOAD(S, P)                                                           \
    { int pc = (P) > 31 ? 31 : (P);                                           \
      const unsigned short* bp = Bbase + (size_t)pc * 32768;                  \
      S##00 = *(const short8*)(bp);                                           \
      S##01 = *(const short8*)(bp + 512);                                     \
      S##10 = *(const short8*)(bp + 16384);                                   \
      S##11 = *(const short8*)(bp + 16384 + 512); }

#define STAGE(Q, R0, R1)                                                      \
    { short8 sv;                                                              \
      sv[0] = f2bf(R0.x); sv[1] = f2bf(R0.y);                                 \
      sv[2] = f2bf(R0.z); sv[3] = f2bf(R0.w);                                 \
      sv[4] = f2bf(R1.x); sv[5] = f2bf(R1.y);                                 \
      sv[6] = f2bf(R1.z); sv[7] = f2bf(R1.w);                                 \
      *(short8*)(swp + (Q) * TILEB) = sv; }

// 16 MFMAs for buffer Q using landed register set S.
#define MFMAS(Q, S)                                                           \
    __builtin_amdgcn_s_setprio(1);                                            \
    _Pragma("unroll")                                                         \
    for (int mi = 0; mi < 8; ++mi){                                           \
        short8 af0 = *(const short8*)(as0 + (Q) * TILEB + mi * 2048);         \
        short8 af1 = *(const short8*)(as1 + (Q) * TILEB + mi * 2048);         \
        acc[mi][0] = MFMA(af0, S##00, acc[mi][0]);                            \
        acc[mi][1] = MFMA(af0, S##01, acc[mi][1]);                            \
        acc[mi][0] = MFMA(af1, S##10, acc[mi][0]);                            \
        acc[mi][1] = MFMA(af1, S##11, acc[mi][1]);                            \
    }                                                                         \
    __builtin_amdgcn_s_setprio(0);

// Raw barrier (m201 pattern): drain LDS ops only; no memory clobber ->
// global loads stay in flight; sched_barrier(0) = compiler fence.
#define PBAR                                                                  \
    __builtin_amdgcn_sched_barrier(0);                                        \
    asm volatile("s_waitcnt lgkmcnt(0)");                                     \
    __builtin_amdgcn_s_barrier();                                             \
    __builtin_amdgcn_sched_barrier(0)

__global__ __launch_bounds__(1024)
void k_main(const float* __restrict__ enc, const unsigned short* __restrict__ Wp,
            const float* __restrict__ benc, const float* __restrict__ att2,
            const float* __restrict__ wfull, float* __restrict__ out,
            float* __restrict__ pawe_ws, float* __restrict__ ms_ws){
    const int wg   = blockIdx.x;            // 0..511
    const int b    = wg >> 3;
    const int tile = wg & 7;
    const int l0   = tile * TM;
    const int tid  = threadIdx.x;
    const int lane = tid & 63, w = tid >> 6;   // w = 0..15 (col-group)

    __shared__ alignas(16) unsigned short Alds[4][TM * 64];  // 4 x 16 KB, XOR-swizzled
    __shared__ float red[16][TM];              // per-wave row score partials (8 KB)
    __shared__ float pl[TM];                   // tile-local exp(s - m)
    __shared__ float mred[2], sred[2];
    char* const alds = (char*)Alds;

    f32x4 acc[8][2];
#pragma unroll
    for (int mi = 0; mi < 8; ++mi)
#pragma unroll
        for (int ni = 0; ni < 2; ++ni)
            acc[mi][ni] = (f32x4){0.f, 0.f, 0.f, 0.f};

    // staging: thread loads 8 fp32 (2x16B) of row (tid>>3), k-chunk (tid&7)*8
    const int srow  = tid >> 3;
    const int sbyte = srow * 128 + (((tid & 7) * 16) ^ ((srow & 7) << 4));
    char* const swp = alds + sbyte;
    const float* apt = enc + ((size_t)(b * Ln + l0 + srow)) * En + (tid & 7) * 8;

    // B fragments: f = (p*2+s)*32 + w*2 + ni ; addr = Wp + f*512 + lane*8
    const unsigned short* Bbase = Wp + (size_t)(w * 2) * 512 + lane * 8;

    // A fragments: row = mi*16 + (lane&15); k-byte = (s*64 + akb) ^ sw (full XOR)
    const int arow = lane & 15;
    const int akb  = (lane >> 4) * 16;
    const int sw   = (arow & 7) << 4;
    const char* const as0 = alds + arow * 128 + (akb ^ sw);
    const char* const as1 = alds + arow * 128 + ((64 + akb) ^ sw);

    // B register sets (double-buffered across phases)
    short8 fa00, fa01, fa10, fa11;   // even phases
    short8 fb00, fb01, fb10, fb11;   // odd phases

    // prologue: tiles 0,1 staged; ring (ra*,rb*) holds tiles 2,3; B(0) in fa
    float4 ra0 = *(const float4*)(apt);
    float4 ra1 = *(const float4*)(apt + 4);
    float4 rb0 = *(const float4*)(apt + 64);
    float4 rb1 = *(const float4*)(apt + 68);
    STAGE(0, ra0, ra1)
    STAGE(1, rb0, rb1)
    ra0 = *(const float4*)(apt + 2 * 64);
    ra1 = *(const float4*)(apt + 2 * 64 + 4);
    rb0 = *(const float4*)(apt + 3 * 64);
    rb1 = *(const float4*)(apt + 3 * 64 + 4);
    BLOAD(fa, 0)

    for (int p = 0; p < 32; p += 4){
        PBAR;
        {   // phase p: issue B(p+1); stage p+2,p+3 -> Q2,Q3; reload ring; MFMA Q0 (fa)
            BLOAD(fb, p + 1)
            STAGE(2, ra0, ra1)
            STAGE(3, rb0, rb1)
            int t0 = p + 4 > 31 ? 31 : p + 4;   // clamped tail loads (unread)
            int t1 = p + 5 > 31 ? 31 : p + 5;
            ra0 = *(const float4*)(apt + t0 * 64);
            ra1 = *(const float4*)(apt + t0 * 64 + 4);
            rb0 = *(const float4*)(apt + t1 * 64);
            rb1 = *(const float4*)(apt + t1 * 64 + 4);
            MFMAS(0, fa)
        }
        {   // phase p+1: issue B(p+2); MFMA Q1 (fb)
            BLOAD(fa, p + 2)
            MFMAS(1, fb)
        }
        PBAR;
        {   // phase p+2: issue B(p+3); stage p+4,p+5 -> Q0,Q1; reload ring; MFMA Q2 (fa)
            BLOAD(fb, p + 3)
            STAGE(0, ra0, ra1)
            STAGE(1, rb0, rb1)
            int t0 = p + 6 > 31 ? 31 : p + 6;
            int t1 = p + 7 > 31 ? 31 : p + 7;
            ra0 = *(const float4*)(apt + t0 * 64);
            ra1 = *(const float4*)(apt + t0 * 64 + 4);
            rb0 = *(const float4*)(apt + t1 * 64);
            rb1 = *(const float4*)(apt + t1 * 64 + 4);
            MFMAS(2, fa)
        }
        {   // phase p+3: issue B(p+4); MFMA Q3 (fb)
            BLOAD(fa, p + 4)
            MFMAS(3, fb)
        }
    }

    // ---- epilogue ----
    float be[2], a2[2], wfv[2];
    const int cbase = w * 32 + (lane & 15);
#pragma unroll
    for (int ni = 0; ni < 2; ++ni){
        int c = cbase + ni * 16;
        be[ni]  = benc[c];
        a2[ni]  = att2[b * An + c];
        wfv[ni] = wfull[c];
    }

    // SPILL FIX: per-mi immediate score reduction — only 4 tsum regs live.
#pragma unroll
    for (int mi = 0; mi < 8; ++mi){
        float ts0 = 0.f, ts1 = 0.f, ts2 = 0.f, ts3 = 0.f;
#pragma unroll
        for (int ni = 0; ni < 2; ++ni){
            float v0 = acc[mi][ni][0] + be[ni]; acc[mi][ni][0] = v0;
            float v1 = acc[mi][ni][1] + be[ni]; acc[mi][ni][1] = v1;
            float v2 = acc[mi][ni][2] + be[ni]; acc[mi][ni][2] = v2;
            float v3 = acc[mi][ni][3] + be[ni]; acc[mi][ni][3] = v3;
            ts0 += tanh_fast(v0 + a2[ni]) * wfv[ni];
            ts1 += tanh_fast(v1 + a2[ni]) * wfv[ni];
            ts2 += tanh_fast(v2 + a2[ni]) * wfv[ni];
            ts3 += tanh_fast(v3 + a2[ni]) * wfv[ni];
        }
        float t4[4] = {ts0, ts1, ts2, ts3};
#pragma unroll
        for (int j = 0; j < 4; ++j){
            float t = t4[j];
            t += __shfl_xor(t, 1); t += __shfl_xor(t, 2);
            t += __shfl_xor(t, 4); t += __shfl_xor(t, 8);
            if ((lane & 15) == 0)
                red[w][mi * 16 + (lane >> 4) * 4 + j] = t;
        }
    }
    __syncthreads();

    // tile softmax over TM=128 rows, handled by waves 0 and 1
    float sc_s = 0.f;
    if (tid < TM){
        const int w2 = tid >> 6;
#pragma unroll
        for (int k = 0; k < 16; ++k)
            sc_s += red[k][tid];
        out[ALPHA_OFF + b * Ln + l0 + tid] = sc_s;   // raw score; finalized in k_final
        float m = sc_s;
        m = fmaxf(m, __shfl_xor(m, 1));  m = fmaxf(m, __shfl_xor(m, 2));
        m = fmaxf(m, __shfl_xor(m, 4));  m = fmaxf(m, __shfl_xor(m, 8));
        m = fmaxf(m, __shfl_xor(m, 16)); m = fmaxf(m, __shfl_xor(m, 32));
        if ((tid & 63) == 0) mred[w2] = m;
    }
    __syncthreads();
    if (tid < TM){
        const int w2 = tid >> 6;
        float mm = fmaxf(mred[0], mred[1]);
        float pv = __expf(sc_s - mm);
        pl[tid] = pv;
        float sm = pv;
        sm += __shfl_xor(sm, 1);  sm += __shfl_xor(sm, 2);
        sm += __shfl_xor(sm, 4);  sm += __shfl_xor(sm, 8);
        sm += __shfl_xor(sm, 16); sm += __shfl_xor(sm, 32);
        if ((tid & 63) == 0) sred[w2] = sm;
    }
    __syncthreads();
    if (tid == 0){
        ms_ws[wg * 2]     = fmaxf(mred[0], mred[1]);
        ms_ws[wg * 2 + 1] = sred[0] + sred[1];
    }

    // partial awe for this wave's 32 cols (ALL 128 rows live in this wave)
    float pp0 = 0.f, pp1 = 0.f;
#pragma unroll
    for (int mi = 0; mi < 8; ++mi)
#pragma unroll
        for (int j = 0; j < 4; ++j){
            float pr = pl[mi * 16 + (lane >> 4) * 4 + j];
            pp0 += pr * acc[mi][0][j];
            pp1 += pr * acc[mi][1][j];
        }
    pp0 += __shfl_xor(pp0, 16); pp0 += __shfl_xor(pp0, 32);
    pp1 += __shfl_xor(pp1, 16); pp1 += __shfl_xor(pp1, 32);
    if (lane < 16){
        pawe_ws[(size_t)wg * An + w * 32 + lane]      = pp0;
        pawe_ws[(size_t)wg * An + w * 32 + 16 + lane] = pp1;
    }
}

// ---------- kernel 2: combine tiles, finalize awe + alpha ----------
__global__ __launch_bounds__(256) void k_final(const float* __restrict__ pawe,
                                               const float* __restrict__ ms,
                                               float* __restrict__ out){
    int b = blockIdx.x, tid = threadIdx.x;
    __shared__ float scale[NTILES];
    __shared__ float sh[2];   // inv_total, global max
    if (tid < 64){
        int lane = tid;
        float m = -1e30f, su = 0.f;
        if (lane < NTILES){ m = ms[(b * NTILES + lane) * 2]; su = ms[(b * NTILES + lane) * 2 + 1]; }
        float mm = m;
        mm = fmaxf(mm, __shfl_xor(mm, 1)); mm = fmaxf(mm, __shfl_xor(mm, 2));
        mm = fmaxf(mm, __shfl_xor(mm, 4));
        float sc = (lane < NTILES) ? su * __expf(m - mm) : 0.f;
        float tot = sc;
        tot += __shfl_xor(tot, 1); tot += __shfl_xor(tot, 2);
        tot += __shfl_xor(tot, 4);
        if (lane < NTILES) scale[lane] = __expf(m - mm);
        if (lane == 0){ sh[0] = 1.0f / tot; sh[1] = mm; }
    }
    __syncthreads();
    float inv = sh[0], mm = sh[1];
    for (int a = tid; a < An; a += 256){
        float s = 0.f;
#pragma unroll
        for (int t = 0; t < NTILES; ++t)
            s += pawe[((size_t)(b * NTILES + t)) * An + a] * scale[t];
        out[AWE_OFF + b * An + a] = s * inv;
    }
    for (int l = tid; l < Ln; l += 256){
        float s = out[ALPHA_OFF + b * Ln + l];
        out[ALPHA_OFF + b * Ln + l] = __expf(s - mm) * inv;
    }
}

extern "C" void kernel_launch(void* const* d_in, const int* in_sizes, int n_in,
                              void* d_out, int out_size, void* d_ws, size_t ws_size,
                              hipStream_t stream){
    const float* enc   = (const float*)d_in[0];
    const float* dh    = (const float*)d_in[1];
    const float* Wenc  = (const float*)d_in[2];
    const float* benc  = (const float*)d_in[3];
    const float* Wdec  = (const float*)d_in[4];
    const float* bdec  = (const float*)d_in[5];
    const float* wfull = (const float*)d_in[6];
    // d_in[7] = b_full: softmax-invariant, unused.
    float* out = (float*)d_out;

    char* ws = (char*)d_ws;
    unsigned short* Wp = (unsigned short*)ws;                       // 2 MB packed W
    float* att2 = (float*)(ws + (2u << 20));                        // 128 KB
    float* pawe = (float*)(ws + (2u << 20) + (128u << 10));         // 1 MB (512 wg x 512)
    float* msb  = (float*)(ws + (4u << 20) + (128u << 10));         // 4 KB

    k_prep<<<576, 256, 0, stream>>>(Wenc, Wp, dh, Wdec, bdec, att2);
    k_main<<<Bn * NTILES, 1024, 0, stream>>>(enc, Wp, benc, att2, wfull, out, pawe, msb);
    k_final<<<Bn, 256, 0, stream>>>(pawe, msb, out);
}

// Round 17
// 244.574 us; speedup vs baseline: 1.5445x; 1.1755x over previous
//
#include <hip/hip_runtime.h>
#include <hip/hip_bf16.h>

// Fused additive-attention (Bahdanau-style) on MI355X.
//   att1 = enc @ W_enc + b_enc            [B,L,A]  (bf16 MFMA, fp32 accum)
//   att2 = dh @ W_dec + b_dec             [B,A]
//   s    = tanh(att1+att2) . W_full       [B,L]    (b_full dropped: softmax-invariant)
//   alpha= softmax_L(s); awe = sum_l alpha * att1  [B,A]
// Flash-style two-level softmax: att1 never hits HBM.
//
// R17 = REVERT to R11 (best measured: 244.9us total).
// Experiment ledger (all measured, all reverted):
//   R7  wave=64x64 (2 w/SIMD)        333us  — ILP regime kills TLP
//   R8  TM=128 (epilogue spill)      318us  — WRITE_SIZE 108MB scratch
//   R9  raw barrier w/ mem clobber   247us  — clobber forces vmcnt(0)
//   R11 lgkm-only barrier (counted)  244.9  — BEST
//   R12 zipper section schedule      263us  — lockstep not the wall
//   R13 producer/consumer waves      258us  — specialization neutral
//   R14 2 blocks/CU (spill)          378us  — 64-col acc doesn't fit 128
//   R15 TM=128 + spill fix           287us  — L2-B volume not the wall
// Structure: TM=64, 16 waves x (64r x 32c), acc[4][2]=32 AGPR, B-reg
// double-set prefetch 1 phase ahead, enc 4-slot ring 4 phases ahead,
// double-buffered XOR-swizzled A-LDS, lgkmcnt-only phase barriers.

#define Bn 64
#define Ln 1024
#define En 2048
#define An 512
#define TM 64          // l-rows per workgroup
#define NTILES (Ln/TM) // 16
#define AWE_OFF 0
#define ALPHA_OFF (Bn*An) // 32768
#define TILEB 8192     // bytes per A k-tile LDS buffer (64 rows x 128B)

using short8 = __attribute__((ext_vector_type(8))) short;
using sh4    = __attribute__((ext_vector_type(4))) short;
using f32x4  = __attribute__((ext_vector_type(4))) float;

__device__ inline short f2bf(float x){
    unsigned u = __builtin_bit_cast(unsigned, x);
    unsigned r = (u + 0x7fffu + ((u >> 16) & 1u)) >> 16;
    return (short)r;
}
__device__ inline float tanh_fast(float x){
    return 2.0f * __frcp_rn(1.0f + __expf(-2.0f * x)) - 1.0f;
}

// ---------- kernel 0: W_enc fragment-pack  +  att2 GEMV (merged) ----------
__global__ __launch_bounds__(256) void k_prep(const float* __restrict__ W,
                                              unsigned short* __restrict__ Wp,
                                              const float* __restrict__ dh,
                                              const float* __restrict__ Wd,
                                              const float* __restrict__ bd,
                                              float* __restrict__ att2){
    __shared__ float dl[512];
    int blk = blockIdx.x, tid = threadIdx.x;
    if (blk < 512){
        int t = blk * 256 + tid;
        int f = t >> 6, lane = t & 63;
        int kb = f >> 5, nc = f & 31;
        int k0 = kb * 32 + (lane >> 4) * 8;
        int col = nc * 16 + (lane & 15);
        short8 v;
#pragma unroll
        for (int j = 0; j < 8; ++j)
            v[j] = f2bf(W[(size_t)(k0 + j) * An + col]);
        *(short8*)(Wp + (size_t)f * 512 + lane * 8) = v;
    } else {
        int b = blk - 512;
        dl[tid]       = dh[b * 512 + tid];
        dl[tid + 256] = dh[b * 512 + tid + 256];
        __syncthreads();
        for (int a = tid; a < An; a += 256){
            float s = bd[a];
            for (int k = 0; k < 512; ++k)
                s = fmaf(dl[k], Wd[(size_t)k * An + a], s);
            att2[b * An + a] = s;
        }
    }
}

// ---------- kernel 1: fused GEMM + score + tile-softmax + partial awe ----------
// 1024 threads = 16 waves, wave w owns rows 0..63 x cols [w*32, w*32+32).

#define MFMA(a, b, c) __builtin_amdgcn_mfma_f32_16x16x32_bf16((a), (b), (c), 0, 0, 0)

// Issue phase-P B loads (4 frags) into set S. P pre-clamped by caller.
#define BLOAD(S, P)                                                           \
    { const unsigned short* bp = Bbase + (size_t)(P) * 32768;                 \
      S##00 = *(const short8*)(bp);                                           \
      S##01 = *(const short8*)(bp + 512);                                     \
      S##10 = *(const short8*)(bp + 16384);                                   \
      S##11 = *(const short8*)(bp + 16384 + 512); }

#define STAGE(Q, R)                                                           \
    { sh4 sv;                                                                 \
      sv[0] = f2bf(R.x); sv[1] = f2bf(R.y);                                   \
      sv[2] = f2bf(R.z); sv[3] = f2bf(R.w);                                   \
      *(sh4*)(swp + (Q) * TILEB) = sv; }

// 16 MFMAs for buffer Q using landed register set S.
#define MFMAS(Q, S)                                                           \
    _Pragma("unroll")                                                         \
    for (int mi = 0; mi < 4; ++mi){                                           \
        short8 af0 = *(const short8*)(as0 + (Q) * TILEB + mi * 2048);         \
        short8 af1 = *(const short8*)(as1 + (Q) * TILEB + mi * 2048);         \
        acc[mi][0] = MFMA(af0, S##00, acc[mi][0]);                            \
        acc[mi][1] = MFMA(af0, S##01, acc[mi][1]);                            \
        acc[mi][0] = MFMA(af1, S##10, acc[mi][0]);                            \
        acc[mi][1] = MFMA(af1, S##11, acc[mi][1]);                            \
    }

// Raw barrier, m201 pattern: drain LDS ops only; NO memory clobber so the
// compiler does NOT force vmcnt(0); sched_barrier(0) is the compiler fence
// keeping ds ops on their side of the barrier.
#define PBAR                                                                  \
    __builtin_amdgcn_sched_barrier(0);                                        \
    asm volatile("s_waitcnt lgkmcnt(0)");                                     \
    __builtin_amdgcn_s_barrier();                                             \
    __builtin_amdgcn_sched_barrier(0)

// One 64-K phase. Reads Q[P&1] with B set FC (landed); stages tile P+1 into
// Q[(P+1)&1] from SLOT (enc, 4 phases old); refills SLOT with enc(P+5);
// issues B(P+1) into FN.
#define PHASE(P, QC, QN, SLOT, FC, FN)                                        \
{                                                                             \
    BLOAD(FN, ((P) + 1 > 31 ? 31 : (P) + 1))                                  \
    STAGE(QN, SLOT)                                                           \
    SLOT = *(const float4*)(apt + ((P) + 5 > 31 ? 31 : (P) + 5) * 64);        \
    __builtin_amdgcn_s_setprio(1);                                            \
    MFMAS(QC, FC)                                                             \
    __builtin_amdgcn_s_setprio(0);                                            \
    PBAR;                                                                     \
}

__global__ __launch_bounds__(1024)
void k_main(const float* __restrict__ enc, const unsigned short* __restrict__ Wp,
            const float* __restrict__ benc, const float* __restrict__ att2,
            const float* __restrict__ wfull, float* __restrict__ out,
            float* __restrict__ pawe_ws, float* __restrict__ ms_ws){
    const int wg   = blockIdx.x;            // 0..1023
    const int b    = wg >> 4;
    const int tile = wg & 15;
    const int l0   = tile * TM;
    const int tid  = threadIdx.x;
    const int lane = tid & 63, w = tid >> 6;   // w = 0..15 (col-group)

    __shared__ alignas(16) unsigned short Alds[2][TM * 64];  // 2 x 8 KB, XOR-swizzled
    __shared__ float red[16][TM];              // per-wave row score partials
    __shared__ float plds[TM];                 // tile-local exp(s - m)
    char* const alds = (char*)Alds;

    f32x4 acc[4][2];
#pragma unroll
    for (int mi = 0; mi < 4; ++mi)
#pragma unroll
        for (int ni = 0; ni < 2; ++ni)
            acc[mi][ni] = (f32x4){0.f, 0.f, 0.f, 0.f};

    // staging: thread loads 4 fp32 (16B) of row (tid>>4), k-chunk (tid&15)*4
    const int srow  = tid >> 4;
    const int sbyte = srow * 128 + (((tid & 15) * 8) ^ ((srow & 7) << 4));
    char* const swp = alds + sbyte;
    const float* apt = enc + ((size_t)(b * Ln + l0 + srow)) * En + (tid & 15) * 4;

    // B fragments: f = (p*2+s)*32 + w*2 + ni ; addr = Wp + f*512 + lane*8
    const unsigned short* Bbase = Wp + (size_t)(w * 2) * 512 + lane * 8;

    // A fragments: row = mi*16 + (lane&15); k-byte = (s*64 + akb) ^ sw (full XOR)
    const int arow = lane & 15;
    const int akb  = (lane >> 4) * 16;
    const int sw   = (arow & 7) << 4;
    const char* const as0 = alds + arow * 128 + (akb ^ sw);
    const char* const as1 = alds + arow * 128 + ((64 + akb) ^ sw);

    // B register sets (double-buffered across phases)
    short8 fa00, fa01, fa10, fa11;   // even phases
    short8 fb00, fb01, fb10, fb11;   // odd phases

    // enc prefetch slots: phase P consumes S[(P+1)&3], refills with enc(P+5).
    float4 S0, S1, S2, S3;

    // prologue: tile 0 staged; slots hold enc(1..4); B(0) in fa.
    float4 e0 = *(const float4*)(apt);
    S1 = *(const float4*)(apt + 64);
    S2 = *(const float4*)(apt + 128);
    S3 = *(const float4*)(apt + 192);
    S0 = *(const float4*)(apt + 256);
    BLOAD(fa, 0)
    STAGE(0, e0)
    PBAR;

    for (int sp = 0; sp < 8; ++sp){
        const int p = sp * 4;
        PHASE(p + 0, 0, 1, S1, fa, fb)
        PHASE(p + 1, 1, 0, S2, fb, fa)
        PHASE(p + 2, 0, 1, S3, fa, fb)
        PHASE(p + 3, 1, 0, S0, fb, fa)
    }

    // ---- epilogue ----
    float be[2], a2[2], wfv[2];
    const int cbase = w * 32 + (lane & 15);
#pragma unroll
    for (int ni = 0; ni < 2; ++ni){
        int c = cbase + ni * 16;
        be[ni]  = benc[c];
        a2[ni]  = att2[b * An + c];
        wfv[ni] = wfull[c];
    }

    float tsum[4][4];
#pragma unroll
    for (int mi = 0; mi < 4; ++mi)
#pragma unroll
        for (int j = 0; j < 4; ++j)
            tsum[mi][j] = 0.f;
#pragma unroll
    for (int mi = 0; mi < 4; ++mi)
#pragma unroll
        for (int ni = 0; ni < 2; ++ni)
#pragma unroll
            for (int j = 0; j < 4; ++j){
                float vv = acc[mi][ni][j] + be[ni];
                acc[mi][ni][j] = vv;
                tsum[mi][j] += tanh_fast(vv + a2[ni]) * wfv[ni];
            }

#pragma unroll
    for (int mi = 0; mi < 4; ++mi)
#pragma unroll
        for (int j = 0; j < 4; ++j){
            float t = tsum[mi][j];
            t += __shfl_xor(t, 1); t += __shfl_xor(t, 2);
            t += __shfl_xor(t, 4); t += __shfl_xor(t, 8);
            if ((lane & 15) == 0)
                red[w][mi * 16 + (lane >> 4) * 4 + j] = t;
        }
    __syncthreads();

    if (tid < 64){   // wave 0: combine 16 wave-partials, tile softmax stats
        float s = 0.f;
#pragma unroll
        for (int k = 0; k < 16; ++k)
            s += red[k][tid];
        out[ALPHA_OFF + b * Ln + l0 + tid] = s;   // raw score; finalized in k_final
        float m = s;
        m = fmaxf(m, __shfl_xor(m, 1));  m = fmaxf(m, __shfl_xor(m, 2));
        m = fmaxf(m, __shfl_xor(m, 4));  m = fmaxf(m, __shfl_xor(m, 8));
        m = fmaxf(m, __shfl_xor(m, 16)); m = fmaxf(m, __shfl_xor(m, 32));
        float pv = __expf(s - m);
        float sm = pv;
        sm += __shfl_xor(sm, 1);  sm += __shfl_xor(sm, 2);
        sm += __shfl_xor(sm, 4);  sm += __shfl_xor(sm, 8);
        sm += __shfl_xor(sm, 16); sm += __shfl_xor(sm, 32);
        plds[tid] = pv;
        if (tid == 0){ ms_ws[wg * 2] = m; ms_ws[wg * 2 + 1] = sm; }
    }
    __syncthreads();

    // partial awe for this wave's 32 cols (rows complete within the wave)
    float pp0 = 0.f, pp1 = 0.f;
#pragma unroll
    for (int mi = 0; mi < 4; ++mi)
#pragma unroll
        for (int j = 0; j < 4; ++j){
            float pr = plds[mi * 16 + (lane >> 4) * 4 + j];
            pp0 += pr * acc[mi][0][j];
            pp1 += pr * acc[mi][1][j];
        }
    pp0 += __shfl_xor(pp0, 16); pp0 += __shfl_xor(pp0, 32);
    pp1 += __shfl_xor(pp1, 16); pp1 += __shfl_xor(pp1, 32);
    if (lane < 16){
        pawe_ws[(size_t)wg * An + w * 32 + lane]      = pp0;
        pawe_ws[(size_t)wg * An + w * 32 + 16 + lane] = pp1;
    }
}

// ---------- kernel 2: combine tiles, finalize awe + alpha ----------
__global__ __launch_bounds__(256) void k_final(const float* __restrict__ pawe,
                                               const float* __restrict__ ms,
                                               float* __restrict__ out){
    int b = blockIdx.x, tid = threadIdx.x;
    __shared__ float scale[NTILES];
    __shared__ float sh[2];   // inv_total, global max
    if (tid < 64){
        int lane = tid;
        float m = -1e30f, su = 0.f;
        if (lane < NTILES){ m = ms[(b * NTILES + lane) * 2]; su = ms[(b * NTILES + lane) * 2 + 1]; }
        float mm = m;
        mm = fmaxf(mm, __shfl_xor(mm, 1)); mm = fmaxf(mm, __shfl_xor(mm, 2));
        mm = fmaxf(mm, __shfl_xor(mm, 4)); mm = fmaxf(mm, __shfl_xor(mm, 8));
        float sc = (lane < NTILES) ? su * __expf(m - mm) : 0.f;
        float tot = sc;
        tot += __shfl_xor(tot, 1); tot += __shfl_xor(tot, 2);
        tot += __shfl_xor(tot, 4); tot += __shfl_xor(tot, 8);
        if (lane < NTILES) scale[lane] = __expf(m - mm);
        if (lane == 0){ sh[0] = 1.0f / tot; sh[1] = mm; }
    }
    __syncthreads();
    float inv = sh[0], mm = sh[1];
    for (int a = tid; a < An; a += 256){
        float s = 0.f;
#pragma unroll
        for (int t = 0; t < NTILES; ++t)
            s += pawe[((size_t)(b * NTILES + t)) * An + a] * scale[t];
        out[AWE_OFF + b * An + a] = s * inv;
    }
    for (int l = tid; l < Ln; l += 256){
        float s = out[ALPHA_OFF + b * Ln + l];
        out[ALPHA_OFF + b * Ln + l] = __expf(s - mm) * inv;
    }
}

extern "C" void kernel_launch(void* const* d_in, const int* in_sizes, int n_in,
                              void* d_out, int out_size, void* d_ws, size_t ws_size,
                              hipStream_t stream){
    const float* enc   = (const float*)d_in[0];
    const float* dh    = (const float*)d_in[1];
    const float* Wenc  = (const float*)d_in[2];
    const float* benc  = (const float*)d_in[3];
    const float* Wdec  = (const float*)d_in[4];
    const float* bdec  = (const float*)d_in[5];
    const float* wfull = (const float*)d_in[6];
    // d_in[7] = b_full: softmax-invariant, unused.
    float* out = (float*)d_out;

    char* ws = (char*)d_ws;
    unsigned short* Wp = (unsigned short*)ws;                       // 2 MB packed W
    float* att2 = (float*)(ws + (2u << 20));                        // 128 KB
    float* pawe = (float*)(ws + (2u << 20) + (128u << 10));         // 2 MB
    float* msb  = (float*)(ws + (4u << 20) + (128u << 10));         // 8 KB

    k_prep<<<576, 256, 0, stream>>>(Wenc, Wp, dh, Wdec, bdec, att2);
    k_main<<<Bn * NTILES, 1024, 0, stream>>>(enc, Wp, benc, att2, wfull, out, pawe, msb);
    k_final<<<Bn, 256, 0, stream>>>(pawe, msb, out);
}